// Round 15
// baseline (307.503 us; speedup 1.0000x reference)
//
#include <hip/hip_runtime.h>
#include <float.h>

#define FEAT 512
#define TOPK 5
#define NSEL 16
#define BM 256                   // attrs per block
#define BN 256                   // imgs per block
#define BKT 64                   // K bytes (i8) per tile
#define NKT (FEAT / BKT)         // 8
#define A_BYTES (BM * BKT)       // 16384
#define BUFB (2 * A_BYTES)       // 32768 per buffer (A+B)
#define NCB 4                    // candidates kept per (img, block)

typedef __attribute__((ext_vector_type(4))) int i32x4;
typedef __attribute__((ext_vector_type(16))) int i32x16;

__device__ __forceinline__ void gl_lds16(const void* g, void* lds) {
    __builtin_amdgcn_global_load_lds(
        (const __attribute__((address_space(1))) unsigned int*)g,
        (__attribute__((address_space(3))) unsigned int*)lds, 16, 0, 0);
}

// ---------- kernel 1a: attr -> int8 with UNIFORM scale 300/||a|| (R8-proven) ----
__global__ __launch_bounds__(256) void quant_attr(
    const float* __restrict__ in, signed char* __restrict__ q,
    float* __restrict__ inv) {
    const int w = threadIdx.x >> 6, l = threadIdx.x & 63;
    const int row = blockIdx.x * 4 + w;
    const float4* p = reinterpret_cast<const float4*>(in) + (size_t)row * (FEAT / 4);
    const float4 v0 = p[l * 2], v1 = p[l * 2 + 1];
    float ss = v0.x * v0.x + v0.y * v0.y + v0.z * v0.z + v0.w * v0.w +
               v1.x * v1.x + v1.y * v1.y + v1.z * v1.z + v1.w * v1.w;
#pragma unroll
    for (int m = 1; m < 64; m <<= 1) ss += __shfl_xor(ss, m);
    const float iv = 1.0f / sqrtf(fmaxf(ss, 1e-30f));
    const float qs = iv * 300.0f;
    int qv[8];
    qv[0] = __float2int_rn(v0.x * qs); qv[1] = __float2int_rn(v0.y * qs);
    qv[2] = __float2int_rn(v0.z * qs); qv[3] = __float2int_rn(v0.w * qs);
    qv[4] = __float2int_rn(v1.x * qs); qv[5] = __float2int_rn(v1.y * qs);
    qv[6] = __float2int_rn(v1.z * qs); qv[7] = __float2int_rn(v1.w * qs);
#pragma unroll
    for (int j = 0; j < 8; ++j) qv[j] = min(127, max(-127, qv[j]));
    int2 st;
    st.x = (qv[0] & 255) | ((qv[1] & 255) << 8) | ((qv[2] & 255) << 16) |
           ((unsigned)(qv[3] & 255) << 24);
    st.y = (qv[4] & 255) | ((qv[5] & 255) << 8) | ((qv[6] & 255) << 16) |
           ((unsigned)(qv[7] & 255) << 24);
    *reinterpret_cast<int2*>(q + (size_t)row * FEAT + l * 8) = st;
    if (l == 0) inv[row] = iv;
}

// ---------- kernel 1b: img -> int8 (per-row max scale) ----------
__global__ __launch_bounds__(256) void quant_img(
    const float* __restrict__ in, signed char* __restrict__ q) {
    const int w = threadIdx.x >> 6, l = threadIdx.x & 63;
    const int row = blockIdx.x * 4 + w;
    const float4* p = reinterpret_cast<const float4*>(in) + (size_t)row * (FEAT / 4);
    const float4 v0 = p[l * 2], v1 = p[l * 2 + 1];
    float mx = fmaxf(fmaxf(fmaxf(fabsf(v0.x), fabsf(v0.y)), fmaxf(fabsf(v0.z), fabsf(v0.w))),
                     fmaxf(fmaxf(fabsf(v1.x), fabsf(v1.y)), fmaxf(fabsf(v1.z), fabsf(v1.w))));
#pragma unroll
    for (int m = 1; m < 64; m <<= 1) mx = fmaxf(mx, __shfl_xor(mx, m));
    mx = fmaxf(mx, 1e-20f);
    const float qs = 127.0f / mx;
    const int q0 = __float2int_rn(v0.x * qs), q1 = __float2int_rn(v0.y * qs);
    const int q2 = __float2int_rn(v0.z * qs), q3 = __float2int_rn(v0.w * qs);
    const int q4 = __float2int_rn(v1.x * qs), q5 = __float2int_rn(v1.y * qs);
    const int q6 = __float2int_rn(v1.z * qs), q7 = __float2int_rn(v1.w * qs);
    int2 st;
    st.x = (q0 & 255) | ((q1 & 255) << 8) | ((q2 & 255) << 16) | ((unsigned)(q3 & 255) << 24);
    st.y = (q4 & 255) | ((q5 & 255) << 8) | ((q6 & 255) << 16) | ((unsigned)(q7 & 255) << 24);
    *reinterpret_cast<int2*>(q + (size_t)row * FEAT + l * 8) = st;
}

// ---------- kernel 2: i8 MFMA coarse, 256x256, 32x32x32 shape ----------
// R9 sync skeleton (STAGE(t+1) -> vmcnt(4) -> barrier -> bulk compute ->
// barrier), dbuf 64KB. Wave tile 128x64 = 4x2 tiles of 32x32; 16 MFMA +
// 12 ds_read per wave-tile. A row=l&31, k-granule=(l>>5)*16B; C row =
// (reg&3)+8*(reg>>2)+4*(l>>5), col=l&31 (guide-verified shape layout).
__global__ __launch_bounds__(512, 2) void coarse_kernel(
    const signed char* __restrict__ attrQ, const signed char* __restrict__ imgQ,
    unsigned* __restrict__ cand, int nablk, int niblk) {
    __shared__ __align__(1024) char lds[2][BUFB];  // 64 KB
    const int tid = threadIdx.x;

    // bijective XCD swizzle (gridDim.x % 8 == 0); iblock fastest (A panel L2-hot)
    const int cpx = gridDim.x >> 3;
    const int wg = ((int)blockIdx.x & 7) * cpx + ((int)blockIdx.x >> 3);
    const int ablock = wg / niblk;
    const int iblock = wg % niblk;

    const int w = tid >> 6, l = tid & 63;
    const int wr = w >> 2, wc = w & 3;
    const int l31 = l & 31, lh = l >> 5;  // row-in-tile, k-granule half

    // ---- staging (pre-swizzled source granule; linear gl_lds dest) ----
    const int srow = tid >> 2, sg = tid & 3;
    const int ssw = sg ^ ((srow ^ (srow >> 2)) & 3);
    const signed char* asrc = attrQ + (size_t)(ablock * BM + srow) * FEAT + (ssw << 4);
    const signed char* bsrc = imgQ + (size_t)(iblock * BN + srow) * FEAT + (ssw << 4);

    // ---- fragment read offsets (swizzled): granule g = ks*2 + lh ----
    int a_off[4][2], b_off[2][2];
#pragma unroll
    for (int m = 0; m < 4; ++m)
#pragma unroll
        for (int ks = 0; ks < 2; ++ks) {
            const int r = wr * 128 + m * 32 + l31;
            const int g = ks * 2 + lh;
            a_off[m][ks] = r * BKT + ((g ^ ((r ^ (r >> 2)) & 3)) << 4);
        }
#pragma unroll
    for (int n = 0; n < 2; ++n)
#pragma unroll
        for (int ks = 0; ks < 2; ++ks) {
            const int r = wc * 64 + n * 32 + l31;
            const int g = ks * 2 + lh;
            b_off[n][ks] = A_BYTES + r * BKT + ((g ^ ((r ^ (r >> 2)) & 3)) << 4);
        }

    i32x16 acc[4][2];
#pragma unroll
    for (int m = 0; m < 4; ++m)
#pragma unroll
        for (int n = 0; n < 2; ++n)
#pragma unroll
            for (int e = 0; e < 16; ++e) acc[m][n][e] = 0;

#define STAGE(bufi, kt)                                                      \
    {                                                                        \
        char* d_ = &lds[bufi][tid * 16];                                     \
        gl_lds16(asrc + (kt) * BKT, d_);                                     \
        gl_lds16(asrc + (kt) * BKT + (size_t)128 * FEAT, d_ + 8192);         \
        gl_lds16(bsrc + (kt) * BKT, d_ + 16384);                             \
        gl_lds16(bsrc + (kt) * BKT + (size_t)128 * FEAT, d_ + 24576);        \
    }

    STAGE(0, 0);
    int cur = 0;
#pragma unroll 1
    for (int t = 0; t < NKT; ++t) {
        if (t < NKT - 1) {
            STAGE(cur ^ 1, t + 1);
            asm volatile("s_waitcnt vmcnt(4)" ::: "memory");  // batch(t) landed
        } else {
            asm volatile("s_waitcnt vmcnt(0)" ::: "memory");
        }
        __builtin_amdgcn_s_barrier();        // everyone's batch(t) visible
        __builtin_amdgcn_sched_barrier(0);   // no reads hoisted above barrier
        const char* buf = &lds[cur][0];
        i32x4 aF[4][2], bF[2][2];
#pragma unroll
        for (int n = 0; n < 2; ++n)
#pragma unroll
            for (int ks = 0; ks < 2; ++ks)
                bF[n][ks] = *reinterpret_cast<const i32x4*>(buf + b_off[n][ks]);
#pragma unroll
        for (int m = 0; m < 4; ++m)
#pragma unroll
            for (int ks = 0; ks < 2; ++ks)
                aF[m][ks] = *reinterpret_cast<const i32x4*>(buf + a_off[m][ks]);
        __builtin_amdgcn_s_setprio(1);
#pragma unroll
        for (int ks = 0; ks < 2; ++ks)
#pragma unroll
            for (int m = 0; m < 4; ++m)
#pragma unroll
                for (int n = 0; n < 2; ++n)
                    acc[m][n] = __builtin_amdgcn_mfma_i32_32x32x32_i8(
                        aF[m][ks], bF[n][ks], acc[m][n], 0, 0, 0);
        __builtin_amdgcn_s_setprio(0);
        __builtin_amdgcn_sched_barrier(0);
        __builtin_amdgcn_s_barrier();        // reads(t) done -> buf reusable
        cur ^= 1;
    }
#undef STAGE

    // ---- fold: integer pack + branchless top-2 per col-group ----
    // attr row = wr*128 + m*32 + (reg&3) + 8*(reg>>2) + 4*lh; col = n*32+l31.
    unsigned m1[2] = {0u, 0u}, m2[2] = {0u, 0u};
#pragma unroll
    for (int m = 0; m < 4; ++m)
#pragma unroll
        for (int reg = 0; reg < 16; ++reg) {
            const int rowl = wr * 128 + m * 32 + (reg & 3) + 8 * (reg >> 2) + 4 * lh;
            const unsigned idxc = 2047u - (unsigned)rowl;
#pragma unroll
            for (int n = 0; n < 2; ++n) {
                const unsigned p =
                    (((unsigned)(acc[m][n][reg] + (1 << 23)) << 8) & 0xFFFFF800u) | idxc;
                m2[n] = max(m2[n], min(m1[n], p));
                m1[n] = max(m1[n], p);
            }
        }

    // merge lane halves (l <-> l^32 share col l&31)
#pragma unroll
    for (int n = 0; n < 2; ++n) {
        const unsigned o1 = __shfl_xor(m1[n], 32);
        const unsigned o2 = __shfl_xor(m2[n], 32);
        m2[n] = max(max(m2[n], o2), min(m1[n], o1));
        m1[n] = max(m1[n], o1);
    }

    __syncthreads();  // K-loop fully done -> reuse buf0 as scratch
    unsigned* scratch = reinterpret_cast<unsigned*>(&lds[0][0]);  // [8][64][2]
    if (lh == 0) {
#pragma unroll
        for (int n = 0; n < 2; ++n) {
            scratch[(w * 64 + n * 32 + l31) * 2 + 0] = m1[n];
            scratch[(w * 64 + n * 32 + l31) * 2 + 1] = m2[n];
        }
    }
    __syncthreads();

    // 256 readers: img col c = tid; merge 2 wr x 2 entries -> top-4
    if (tid < BN) {
        const int wc2 = tid >> 6, lc = tid & 63;
        unsigned best[NCB] = {0u, 0u, 0u, 0u};
#pragma unroll
        for (int wr2 = 0; wr2 < 2; ++wr2)
#pragma unroll
            for (int k = 0; k < 2; ++k) {
                const unsigned p = scratch[((wr2 * 4 + wc2) * 64 + lc) * 2 + k];
                if (p > best[NCB - 1]) {
                    best[NCB - 1] = p;
#pragma unroll
                    for (int x = NCB - 1; x > 0; --x)
                        if (best[x] > best[x - 1]) {
                            const unsigned t_ = best[x];
                            best[x] = best[x - 1]; best[x - 1] = t_;
                        }
                }
            }
        const size_t base = ((size_t)(iblock * BN + tid) * nablk + ablock) * NCB;
#pragma unroll
        for (int j = 0; j < NCB; ++j) cand[base + j] = best[j];
    }
}

// ---------- kernel 3 (FUSED): select top-16 -> fp32 rescore -> top-5 -> gather ----
__global__ __launch_bounds__(256) void final_kernel(
    const float* __restrict__ img, const float* __restrict__ attr,
    const float* __restrict__ inv, const unsigned* __restrict__ cand,
    float* __restrict__ out0, float* __restrict__ out_scores, int nablk) {
    __shared__ int s_sel[NSEL];
    __shared__ float s_sc[NSEL];
    __shared__ int s_fi[TOPK];
    const int row = blockIdx.x;
    const int tid = threadIdx.x;
    const int w = tid >> 6, l = tid & 63;

    // phase 1: wave 0 merges nablk*NCB packed candidates -> top-16 indices
    if (w == 0) {
        const int ncand = nablk * NCB;  // 1000
        const unsigned* cr = cand + (size_t)row * ncand;
        unsigned p[16]; int c[16];
#pragma unroll
        for (int j = 0; j < 16; ++j) {
            const int slot = l * 16 + j;
            if (slot < ncand) {
                const unsigned v = cr[slot];
                p[j] = v;
                c[j] = (slot / NCB) * BM + (2047 - (int)(v & 0x7FFu));
            } else { p[j] = 0u; c[j] = 0x7fffffff; }
        }
        for (int r = 0; r < NSEL; ++r) {
            unsigned bp = 0u; int bc = 0x7fffffff;
#pragma unroll
            for (int j = 0; j < 16; ++j)
                if (p[j] > bp || (p[j] == bp && c[j] < bc)) { bp = p[j]; bc = c[j]; }
#pragma unroll
            for (int m = 1; m < 64; m <<= 1) {
                const unsigned op = __shfl_xor(bp, m);
                const int oc = __shfl_xor(bc, m);
                if (op > bp || (op == bp && oc < bc)) { bp = op; bc = oc; }
            }
            if (l == 0) s_sel[r] = bc;
#pragma unroll
            for (int j = 0; j < 16; ++j)
                if (p[j] == bp && c[j] == bc) { p[j] = 0u; c[j] = 0x7fffffff; }
        }
    }
    __syncthreads();

    // phase 2: exact fp32 rescore of the 16 candidates (4 waves x 4 slots)
    const float4* ip = reinterpret_cast<const float4*>(img) + (size_t)row * (FEAT / 4);
    const float4 a0 = ip[l * 2], a1 = ip[l * 2 + 1];
#pragma unroll
    for (int q = 0; q < 4; ++q) {
        const int slot = w * 4 + q;
        const int ci = s_sel[slot];
        const float4* ap = reinterpret_cast<const float4*>(attr) + (size_t)ci * (FEAT / 4);
        const float4 b0 = ap[l * 2], b1 = ap[l * 2 + 1];
        float d = a0.x * b0.x + a0.y * b0.y + a0.z * b0.z + a0.w * b0.w +
                  a1.x * b1.x + a1.y * b1.y + a1.z * b1.z + a1.w * b1.w;
#pragma unroll
        for (int m = 1; m < 64; m <<= 1) d += __shfl_xor(d, m);
        if (l == 0) s_sc[slot] = d * inv[ci];
    }
    __syncthreads();

    // phase 3: thread 0 final top-5 (score desc, index asc on ties)
    if (tid == 0) {
        float ts[TOPK]; int ti[TOPK];
#pragma unroll
        for (int j = 0; j < TOPK; ++j) { ts[j] = -FLT_MAX; ti[j] = 0x7fffffff; }
        for (int e = 0; e < NSEL; ++e) {
            const float sv = s_sc[e];
            const int iv = s_sel[e];
            if (sv > ts[4] || (sv == ts[4] && iv < ti[4])) {
                ts[4] = sv; ti[4] = iv;
#pragma unroll
                for (int x = 4; x > 0; --x)
                    if (ts[x] > ts[x - 1] || (ts[x] == ts[x - 1] && ti[x] < ti[x - 1])) {
                        const float tf = ts[x]; ts[x] = ts[x - 1]; ts[x - 1] = tf;
                        const int td = ti[x]; ti[x] = ti[x - 1]; ti[x - 1] = td;
                    }
            }
        }
#pragma unroll
        for (int j = 0; j < TOPK; ++j) {
            out_scores[(size_t)row * TOPK + j] = ts[j];
            s_fi[j] = ti[j];
        }
    }
    __syncthreads();

    // phase 4: gather normalized winners (rows are L2-hot from phase 2)
    for (int e = tid; e < TOPK * (FEAT / 4); e += 256) {
        const int j = e >> 7, t4 = e & (FEAT / 4 - 1);
        const int fi = s_fi[j];
        const float sc = inv[fi];
        const float4 v = reinterpret_cast<const float4*>(attr)[(size_t)fi * (FEAT / 4) + t4];
        float4 o;
        o.x = v.x * sc; o.y = v.y * sc; o.z = v.z * sc; o.w = v.w * sc;
        reinterpret_cast<float4*>(out0)[((size_t)row * TOPK + j) * (FEAT / 4) + t4] = o;
    }
}

extern "C" void kernel_launch(void* const* d_in, const int* in_sizes, int n_in,
                              void* d_out, int out_size, void* d_ws, size_t ws_size,
                              hipStream_t stream) {
    const float* img = (const float*)d_in[0];
    const float* attr = (const float*)d_in[1];
    const int batch = in_sizes[0] / FEAT;  // 4096
    const int nattr = in_sizes[1] / FEAT;  // 64000
    const int nablk = nattr / BM;          // 250
    const int niblk = batch / BN;          // 16

    // workspace layout (~52 MB, 16B-aligned segments)
    char* ws = (char*)d_ws;
    signed char* attrQ = (signed char*)ws; ws += (size_t)nattr * FEAT;
    signed char* imgQ = (signed char*)ws;  ws += (size_t)batch * FEAT;
    float* inv = (float*)ws;               ws += (size_t)nattr * 4;
    unsigned* cand = (unsigned*)ws;        ws += (size_t)batch * nablk * NCB * 4;

    float* out0 = (float*)d_out;                             // [batch][5][512]
    float* out_scores = out0 + (size_t)batch * TOPK * FEAT;  // [batch][5]

    quant_attr<<<nattr / 4, 256, 0, stream>>>(attr, attrQ, inv);
    quant_img<<<batch / 4, 256, 0, stream>>>(img, imgQ);
    coarse_kernel<<<nablk * niblk, 512, 0, stream>>>(attrQ, imgQ, cand, nablk, niblk);
    final_kernel<<<batch, 256, 0, stream>>>(img, attr, inv, cand, out0, out_scores,
                                            nablk);
}

// Round 17
// 272.001 us; speedup vs baseline: 1.1305x; 1.1305x over previous
//
#include <hip/hip_runtime.h>
#include <float.h>

#define FEAT 512
#define TOPK 5
#define NSEL 16
#define BM 256                   // attrs per block
#define BN 256                   // imgs per block
#define BKT 64                   // K bytes (i8) per tile
#define NKT (FEAT / BKT)         // 8
#define ABYTES (BM * BKT)        // 16384 per operand per buffer
#define BUFB (2 * ABYTES)        // 32768 per buffer
#define NCB 4                    // candidates kept per (img, block)

typedef __attribute__((ext_vector_type(4))) int i32x4;

__device__ __forceinline__ void gl_lds16(const void* g, void* lds) {
    __builtin_amdgcn_global_load_lds(
        (const __attribute__((address_space(1))) unsigned int*)g,
        (__attribute__((address_space(3))) unsigned int*)lds, 16, 0, 0);
}

// ---------- kernel 1: fused quantization ----------
// blocks [0, nattrblk): attr rows -> UNIFORM scale 300/||a|| (R8-proven) + inv.
// blocks [nattrblk, ...): img rows -> per-row max scale (positive per-img
// factor leaves per-img ranking invariant).
__global__ __launch_bounds__(256) void quant_fused(
    const float* __restrict__ attr, const float* __restrict__ img,
    signed char* __restrict__ attrQ, signed char* __restrict__ imgQ,
    float* __restrict__ inv, int nattrblk) {
    const int w = threadIdx.x >> 6, l = threadIdx.x & 63;
    const bool isattr = (int)blockIdx.x < nattrblk;
    const int row = (isattr ? (int)blockIdx.x : (int)blockIdx.x - nattrblk) * 4 + w;
    const float* src = isattr ? attr : img;
    const float4* p = reinterpret_cast<const float4*>(src) + (size_t)row * (FEAT / 4);
    const float4 v0 = p[l * 2], v1 = p[l * 2 + 1];
    float qs;
    if (isattr) {
        float ss = v0.x * v0.x + v0.y * v0.y + v0.z * v0.z + v0.w * v0.w +
                   v1.x * v1.x + v1.y * v1.y + v1.z * v1.z + v1.w * v1.w;
#pragma unroll
        for (int m = 1; m < 64; m <<= 1) ss += __shfl_xor(ss, m);
        const float iv = 1.0f / sqrtf(fmaxf(ss, 1e-30f));
        qs = iv * 300.0f;
        if (l == 0) inv[row] = iv;
    } else {
        float mx = fmaxf(fmaxf(fmaxf(fabsf(v0.x), fabsf(v0.y)), fmaxf(fabsf(v0.z), fabsf(v0.w))),
                         fmaxf(fmaxf(fabsf(v1.x), fabsf(v1.y)), fmaxf(fabsf(v1.z), fabsf(v1.w))));
#pragma unroll
        for (int m = 1; m < 64; m <<= 1) mx = fmaxf(mx, __shfl_xor(mx, m));
        qs = 127.0f / fmaxf(mx, 1e-20f);
    }
    int qv[8];
    qv[0] = __float2int_rn(v0.x * qs); qv[1] = __float2int_rn(v0.y * qs);
    qv[2] = __float2int_rn(v0.z * qs); qv[3] = __float2int_rn(v0.w * qs);
    qv[4] = __float2int_rn(v1.x * qs); qv[5] = __float2int_rn(v1.y * qs);
    qv[6] = __float2int_rn(v1.z * qs); qv[7] = __float2int_rn(v1.w * qs);
#pragma unroll
    for (int j = 0; j < 8; ++j) qv[j] = min(127, max(-127, qv[j]));
    int2 st;
    st.x = (qv[0] & 255) | ((qv[1] & 255) << 8) | ((qv[2] & 255) << 16) |
           ((unsigned)(qv[3] & 255) << 24);
    st.y = (qv[4] & 255) | ((qv[5] & 255) << 8) | ((qv[6] & 255) << 16) |
           ((unsigned)(qv[7] & 255) << 24);
    signed char* dst = isattr ? attrQ : imgQ;
    *reinterpret_cast<int2*>(dst + (size_t)row * FEAT + l * 8) = st;
}

// ---------- kernel 2: i8 MFMA coarse, 256x256 tile (R9 verbatim, 190us) ----------
// 8 waves (2M x 4N), wave tile 128x64, acc[8][4]. LDS 2x32KB dbuf, XOR swizzle.
// Per tile: stage(t+1) -> vmcnt(4) -> barrier -> 4 phases {2 A-frag ds_read,
// lgkmcnt(0), setprio, 8 MFMA} -> barrier. Fold: int pack + top-2/bucket.
__global__ __launch_bounds__(512, 2) void coarse_kernel(
    const signed char* __restrict__ attrQ, const signed char* __restrict__ imgQ,
    unsigned* __restrict__ cand, int nablk, int niblk) {
    __shared__ __align__(1024) char lds[2][BUFB];  // 64 KB
    const int tid = threadIdx.x;

    // bijective XCD swizzle (gridDim.x % 8 == 0); iblock fastest (A panel L2-hot)
    const int cpx = gridDim.x >> 3;
    const int wg = ((int)blockIdx.x & 7) * cpx + ((int)blockIdx.x >> 3);
    const int ablock = wg / niblk;
    const int iblock = wg % niblk;

    const int w = tid >> 6, l = tid & 63;
    const int wr = w >> 2, wc = w & 3;
    const int lrow = l & 15, lg = l >> 4;

    // ---- staging (pre-swizzled source granule; linear gl_lds dest) ----
    const int srow = tid >> 2, sg = tid & 3;
    const int ssw = sg ^ ((srow ^ (srow >> 2)) & 3);
    const signed char* asrc = attrQ + (size_t)(ablock * BM + srow) * FEAT + (ssw << 4);
    const signed char* bsrc = imgQ + (size_t)(iblock * BN + srow) * FEAT + (ssw << 4);

    // ---- fragment read offsets (swizzled) ----
    int a_off[8], b_off[4];
#pragma unroll
    for (int m = 0; m < 8; ++m) {
        const int r = wr * 128 + m * 16 + lrow;
        a_off[m] = r * BKT + ((lg ^ ((r ^ (r >> 2)) & 3)) << 4);
    }
#pragma unroll
    for (int n = 0; n < 4; ++n) {
        const int r = wc * 64 + n * 16 + lrow;
        b_off[n] = ABYTES + r * BKT + ((lg ^ ((r ^ (r >> 2)) & 3)) << 4);
    }

    i32x4 acc[8][4];
#pragma unroll
    for (int m = 0; m < 8; ++m)
#pragma unroll
        for (int n = 0; n < 4; ++n) acc[m][n] = (i32x4){0, 0, 0, 0};

#define STAGE(bufi, kt)                                                      \
    {                                                                        \
        char* d_ = &lds[bufi][tid * 16];                                     \
        gl_lds16(asrc + (kt) * BKT, d_);                                     \
        gl_lds16(asrc + (kt) * BKT + (size_t)128 * FEAT, d_ + 8192);         \
        gl_lds16(bsrc + (kt) * BKT, d_ + 16384);                             \
        gl_lds16(bsrc + (kt) * BKT + (size_t)128 * FEAT, d_ + 24576);        \
    }

    STAGE(0, 0);
#pragma unroll 1
    for (int t = 0; t < NKT; ++t) {
        const int cur = t & 1;
        const char* buf = &lds[cur][0];
        if (t < NKT - 1) STAGE(cur ^ 1, t + 1);  // buf^1 free: t-1 end-barrier passed
        __builtin_amdgcn_sched_barrier(0);
        if (t < NKT - 1) {
            asm volatile("s_waitcnt vmcnt(4)" ::: "memory");  // batch(t) retired
        } else {
            asm volatile("s_waitcnt vmcnt(0)" ::: "memory");
        }
        __builtin_amdgcn_s_barrier();  // all waves' batch(t) visible
        __builtin_amdgcn_sched_barrier(0);

        // B fragments for the whole tile (wait folded into phase 0 lgkmcnt)
        i32x4 bF[4];
#pragma unroll
        for (int n = 0; n < 4; ++n)
            bF[n] = *reinterpret_cast<const i32x4*>(buf + b_off[n]);

        // 4 phases: {2 A-frag ds_read | lgkm(0) | setprio | 8 MFMA}
#pragma unroll
        for (int p = 0; p < 4; ++p) {
            const i32x4 aF0 = *reinterpret_cast<const i32x4*>(buf + a_off[2 * p]);
            const i32x4 aF1 = *reinterpret_cast<const i32x4*>(buf + a_off[2 * p + 1]);
            asm volatile("s_waitcnt lgkmcnt(0)" ::: "memory");
            __builtin_amdgcn_sched_barrier(0);
            __builtin_amdgcn_s_setprio(1);
#pragma unroll
            for (int n = 0; n < 4; ++n)
                acc[2 * p][n] = __builtin_amdgcn_mfma_i32_16x16x64_i8(
                    aF0, bF[n], acc[2 * p][n], 0, 0, 0);
#pragma unroll
            for (int n = 0; n < 4; ++n)
                acc[2 * p + 1][n] = __builtin_amdgcn_mfma_i32_16x16x64_i8(
                    aF1, bF[n], acc[2 * p + 1][n], 0, 0, 0);
            __builtin_amdgcn_s_setprio(0);
            __builtin_amdgcn_sched_barrier(0);
        }
        __builtin_amdgcn_s_barrier();  // tile reads done -> buf reusable
        __builtin_amdgcn_sched_barrier(0);
    }
#undef STAGE

    // ---- fold: integer pack (R8-proven) + branchless top-2 per 16-attr bucket ----
    // |idot| <= 512*127*127 = 8.26M < 2^23.
    unsigned m1[4] = {0u, 0u, 0u, 0u}, m2[4] = {0u, 0u, 0u, 0u};
#pragma unroll
    for (int m = 0; m < 8; ++m)
#pragma unroll
        for (int r = 0; r < 4; ++r) {
            const int rowl = wr * 128 + m * 16 + lg * 4 + r;  // local attr 0..255
            const unsigned idxc = 2047u - (unsigned)rowl;
#pragma unroll
            for (int n = 0; n < 4; ++n) {
                const unsigned p =
                    (((unsigned)(acc[m][n][r] + (1 << 23)) << 8) & 0xFFFFF800u) | idxc;
                m2[n] = max(m2[n], min(m1[n], p));
                m1[n] = max(m1[n], p);
            }
        }

    // per-lane top-2 per n-group -> LDS scratch (K-loop LDS fully drained)
    unsigned* scratch = reinterpret_cast<unsigned*>(&lds[0][0]);  // [8][64][8]
#pragma unroll
    for (int n = 0; n < 4; ++n) {
        scratch[(w * 64 + l) * 8 + n * 2] = m1[n];
        scratch[(w * 64 + l) * 8 + n * 2 + 1] = m2[n];
    }
    __syncthreads();

    // 256 readers: img col c = tid; merge 2 wr x 4 lg x 2 = 16 -> top-4
    if (tid < BN) {
        const int wc2 = tid >> 6, cw = tid & 63;
        const int n = cw >> 4, lr = cw & 15;
        unsigned best[NCB] = {0u, 0u, 0u, 0u};
#pragma unroll
        for (int wr2 = 0; wr2 < 2; ++wr2)
#pragma unroll
            for (int lg2 = 0; lg2 < 4; ++lg2)
#pragma unroll
                for (int k = 0; k < 2; ++k) {
                    const unsigned p =
                        scratch[((wr2 * 4 + wc2) * 64 + lg2 * 16 + lr) * 8 + n * 2 + k];
                    if (p > best[NCB - 1]) {
                        best[NCB - 1] = p;
#pragma unroll
                        for (int x = NCB - 1; x > 0; --x)
                            if (best[x] > best[x - 1]) {
                                const unsigned t_ = best[x];
                                best[x] = best[x - 1]; best[x - 1] = t_;
                            }
                    }
                }
        const size_t base = ((size_t)(iblock * BN + tid) * nablk + ablock) * NCB;
#pragma unroll
        for (int j = 0; j < NCB; ++j) cand[base + j] = best[j];
    }
}

// ---------- kernel 3: per-img merge of nablk*4 packed candidates -> top-16 ----------
__global__ __launch_bounds__(64) void select16_kernel(
    const unsigned* __restrict__ cand, int* __restrict__ sel, int nablk) {
    const int row = blockIdx.x;
    const int l = threadIdx.x;
    const int ncand = nablk * NCB;  // 1000
    const unsigned* cr = cand + (size_t)row * ncand;
    unsigned p[16]; int c[16];
#pragma unroll
    for (int j = 0; j < 16; ++j) {
        const int slot = l * 16 + j;
        if (slot < ncand) {
            const unsigned v = cr[slot];
            p[j] = v;
            c[j] = (slot / NCB) * BM + (2047 - (int)(v & 0x7FFu));
        } else { p[j] = 0u; c[j] = 0x7fffffff; }
    }
    int* out = sel + (size_t)row * NSEL;
    for (int r = 0; r < NSEL; ++r) {
        unsigned bp = 0u; int bc = 0x7fffffff;
#pragma unroll
        for (int j = 0; j < 16; ++j)
            if (p[j] > bp || (p[j] == bp && c[j] < bc)) { bp = p[j]; bc = c[j]; }
#pragma unroll
        for (int m = 1; m < 64; m <<= 1) {
            const unsigned op = __shfl_xor(bp, m);
            const int oc = __shfl_xor(bc, m);
            if (op > bp || (op == bp && oc < bc)) { bp = op; bc = oc; }
        }
        if (l == 0) out[r] = bc;
#pragma unroll
        for (int j = 0; j < 16; ++j)
            if (p[j] == bp && c[j] == bc) { p[j] = 0u; c[j] = 0x7fffffff; }
    }
}

// ---------- kernel 4: exact fp32 rescore of 16 candidates -> top-5 + gather ----------
__global__ __launch_bounds__(256) void rescore_gather(
    const float* __restrict__ img, const float* __restrict__ attr,
    const float* __restrict__ inv, const int* __restrict__ sel,
    float* __restrict__ out0, float* __restrict__ out_scores) {
    __shared__ float s_sc[NSEL];
    __shared__ int s_fi[TOPK];
    const int row = blockIdx.x;
    const int tid = threadIdx.x;
    const int w = tid >> 6, l = tid & 63;

    // rescore: 4 waves x 4 slots (R14-proven mapping)
    const float4* ip = reinterpret_cast<const float4*>(img) + (size_t)row * (FEAT / 4);
    const float4 a0 = ip[l * 2], a1 = ip[l * 2 + 1];
#pragma unroll
    for (int q = 0; q < 4; ++q) {
        const int slot = w * 4 + q;
        const int ci = sel[(size_t)row * NSEL + slot];
        const float4* ap = reinterpret_cast<const float4*>(attr) + (size_t)ci * (FEAT / 4);
        const float4 b0 = ap[l * 2], b1 = ap[l * 2 + 1];
        float d = a0.x * b0.x + a0.y * b0.y + a0.z * b0.z + a0.w * b0.w +
                  a1.x * b1.x + a1.y * b1.y + a1.z * b1.z + a1.w * b1.w;
#pragma unroll
        for (int m = 1; m < 64; m <<= 1) d += __shfl_xor(d, m);
        if (l == 0) s_sc[slot] = d * inv[ci];
    }
    __syncthreads();

    // thread 0: final top-5 (score desc, index asc on ties)
    if (tid == 0) {
        float ts[TOPK]; int ti[TOPK];
#pragma unroll
        for (int j = 0; j < TOPK; ++j) { ts[j] = -FLT_MAX; ti[j] = 0x7fffffff; }
        for (int e = 0; e < NSEL; ++e) {
            const float sv = s_sc[e];
            const int iv = sel[(size_t)row * NSEL + e];
            if (sv > ts[4] || (sv == ts[4] && iv < ti[4])) {
                ts[4] = sv; ti[4] = iv;
#pragma unroll
                for (int x = 4; x > 0; --x)
                    if (ts[x] > ts[x - 1] || (ts[x] == ts[x - 1] && ti[x] < ti[x - 1])) {
                        const float tf = ts[x]; ts[x] = ts[x - 1]; ts[x - 1] = tf;
                        const int td = ti[x]; ti[x] = ti[x - 1]; ti[x - 1] = td;
                    }
            }
        }
#pragma unroll
        for (int j = 0; j < TOPK; ++j) {
            out_scores[(size_t)row * TOPK + j] = ts[j];
            s_fi[j] = ti[j];
        }
    }
    __syncthreads();

    // gather normalized winners (rows L2-hot from rescore)
    for (int e = tid; e < TOPK * (FEAT / 4); e += 256) {
        const int j = e >> 7, t4 = e & (FEAT / 4 - 1);
        const int fi = s_fi[j];
        const float sc = inv[fi];
        const float4 v = reinterpret_cast<const float4*>(attr)[(size_t)fi * (FEAT / 4) + t4];
        float4 o;
        o.x = v.x * sc; o.y = v.y * sc; o.z = v.z * sc; o.w = v.w * sc;
        reinterpret_cast<float4*>(out0)[((size_t)row * TOPK + j) * (FEAT / 4) + t4] = o;
    }
}

extern "C" void kernel_launch(void* const* d_in, const int* in_sizes, int n_in,
                              void* d_out, int out_size, void* d_ws, size_t ws_size,
                              hipStream_t stream) {
    const float* img = (const float*)d_in[0];
    const float* attr = (const float*)d_in[1];
    const int batch = in_sizes[0] / FEAT;  // 4096
    const int nattr = in_sizes[1] / FEAT;  // 64000
    const int nablk = nattr / BM;          // 250
    const int niblk = batch / BN;          // 16

    // workspace layout (~52 MB, 16B-aligned segments)
    char* ws = (char*)d_ws;
    signed char* attrQ = (signed char*)ws; ws += (size_t)nattr * FEAT;
    signed char* imgQ = (signed char*)ws;  ws += (size_t)batch * FEAT;
    float* inv = (float*)ws;               ws += (size_t)nattr * 4;
    unsigned* cand = (unsigned*)ws;        ws += (size_t)batch * nablk * NCB * 4;
    int* sel = (int*)ws;                   ws += (size_t)batch * NSEL * 4;

    float* out0 = (float*)d_out;                             // [batch][5][512]
    float* out_scores = out0 + (size_t)batch * TOPK * FEAT;  // [batch][5]

    quant_fused<<<nattr / 4 + batch / 4, 256, 0, stream>>>(attr, img, attrQ, imgQ,
                                                           inv, nattr / 4);
    coarse_kernel<<<nablk * niblk, 512, 0, stream>>>(attrQ, imgQ, cand, nablk, niblk);
    select16_kernel<<<batch, 64, 0, stream>>>(cand, sel, nablk);
    rescore_gather<<<batch, 256, 0, stream>>>(img, attr, inv, sel, out0, out_scores);
}